// Round 23
// baseline (184.149 us; speedup 1.0000x reference)
//
#include <hip/hip_runtime.h>
#include <hip/hip_bf16.h>

typedef __attribute__((ext_vector_type(8))) __bf16 bf16x8;
typedef __attribute__((ext_vector_type(8))) short s16x8;
typedef __attribute__((ext_vector_type(4))) float f32x4;

#define NB 2
#define NS 4096
#define ND 512
#define NH 8
#define NHD 64
#define NMLP 2048

__device__ __forceinline__ unsigned short f2b(float f) {
  __hip_bfloat16 h = __float2bfloat16(f);
  return __builtin_bit_cast(unsigned short, h);
}

__device__ __forceinline__ float b2f(unsigned short u) {
  unsigned int x = (unsigned int)u << 16;
  return __builtin_bit_cast(float, x);
}

// gelu(x) = x * sigmoid(2u), u = 0.79788456(x + 0.044715 x^3)
__device__ __forceinline__ float geluf(float x) {
  float u = 0.7978845608028654f * (x + 0.044715f * x * x * x);
  return x / (1.0f + __expf(-2.0f * u));
}

// raw v_exp_f32: 2^x (attention scores kept in log2 domain)
__device__ __forceinline__ float exp2_fast(float x) {
  float r;
  asm("v_exp_f32 %0, %1" : "=v"(r) : "v"(x));
  return r;
}

__device__ __forceinline__ void gload16(const void* g, void* l) {
  __builtin_amdgcn_global_load_lds((const __attribute__((address_space(1))) void*)g,
                                   (__attribute__((address_space(3))) void*)l, 16, 0, 0);
}

// ---- fused: weight transposes (blocks 0..767) + LayerNorm1 (blocks 768..2815) ----
// wq gets 0.125*log2(e) baked in (attention softmax runs in log2 domain).
__global__ __launch_bounds__(256) void prep_ln(const float* __restrict__ wq,
                                               const float* __restrict__ wk,
                                               const float* __restrict__ wv,
                                               const float* __restrict__ wo,
                                               const float* __restrict__ w1,
                                               const float* __restrict__ w2,
                                               unsigned short* __restrict__ qkvT,
                                               unsigned short* __restrict__ woT,
                                               unsigned short* __restrict__ w1T,
                                               unsigned short* __restrict__ w2T,
                                               const float* __restrict__ x,
                                               const float* __restrict__ g,
                                               const float* __restrict__ bta,
                                               unsigned short* __restrict__ xout) {
  __shared__ unsigned short lt[64][66];
  const int t = threadIdx.x;
  if (blockIdx.x < 768) {
    const int tile = blockIdx.x;
    const float* src;
    unsigned short* dst;
    int R, C, tr, tc;
    float sc = 1.0f;
    if (tile < 256) {
      int seg = tile >> 6, tt = tile & 63;
      R = 512; C = 512;
      src = seg == 0 ? wq : seg == 1 ? wk : seg == 2 ? wv : wo;
      dst = (seg < 3) ? (qkvT + ((size_t)seg << 18)) : woT;
      if (seg == 0) sc = 0.18033688011112042f;  // 0.125 * log2(e)
      tr = tt >> 3; tc = tt & 7;
    } else if (tile < 512) {
      int tt = tile - 256;
      R = 512; C = 2048; src = w1; dst = w1T;
      tr = tt >> 5; tc = tt & 31;
    } else {
      int tt = tile - 512;
      R = 2048; C = 512; src = w2; dst = w2T;
      tr = tt >> 3; tc = tt & 7;
    }
    const int r0 = tr * 64, c0 = tc * 64;
    const int fx = t & 15, fy = t >> 4;
#pragma unroll
    for (int p = 0; p < 4; ++p) {
      int rr = p * 16 + fy;
      float4 v = *(const float4*)&src[(size_t)(r0 + rr) * C + c0 + fx * 4];
      lt[rr][fx * 4 + 0] = f2b(v.x * sc);
      lt[rr][fx * 4 + 1] = f2b(v.y * sc);
      lt[rr][fx * 4 + 2] = f2b(v.z * sc);
      lt[rr][fx * 4 + 3] = f2b(v.w * sc);
    }
    __syncthreads();
#pragma unroll
    for (int p = 0; p < 4; ++p) {
      int cc = p * 16 + fy;
      ushort4 o;
      o.x = lt[fx * 4 + 0][cc];
      o.y = lt[fx * 4 + 1][cc];
      o.z = lt[fx * 4 + 2][cc];
      o.w = lt[fx * 4 + 3][cc];
      *(ushort4*)&dst[(size_t)(c0 + cc) * R + r0 + fx * 4] = o;
    }
  } else {
    const int l = t & 63, w = t >> 6;
    const size_t row = (size_t)(blockIdx.x - 768) * 4 + w;
    const float4* xr = (const float4*)(x + row * ND);
    float4 a = xr[l];
    float4 bq = xr[64 + l];
    float s = a.x + a.y + a.z + a.w + bq.x + bq.y + bq.z + bq.w;
    float ss = a.x * a.x + a.y * a.y + a.z * a.z + a.w * a.w +
               bq.x * bq.x + bq.y * bq.y + bq.z * bq.z + bq.w * bq.w;
#pragma unroll
    for (int msk = 1; msk <= 32; msk <<= 1) {
      s += __shfl_xor(s, msk);
      ss += __shfl_xor(ss, msk);
    }
    float mu = s * (1.0f / ND);
    float var = ss * (1.0f / ND) - mu * mu;
    float rr = rsqrtf(var + 1e-6f);
    const float4* g4 = (const float4*)g;
    const float4* b4 = (const float4*)bta;
    float4 g0 = g4[l], g1 = g4[64 + l], b0 = b4[l], b1 = b4[64 + l];
    ushort4 o0, o1;
    o0.x = f2b((a.x - mu) * rr * g0.x + b0.x);
    o0.y = f2b((a.y - mu) * rr * g0.y + b0.y);
    o0.z = f2b((a.z - mu) * rr * g0.z + b0.z);
    o0.w = f2b((a.w - mu) * rr * g0.w + b0.w);
    o1.x = f2b((bq.x - mu) * rr * g1.x + b1.x);
    o1.y = f2b((bq.y - mu) * rr * g1.y + b1.y);
    o1.z = f2b((bq.z - mu) * rr * g1.z + b1.z);
    o1.w = f2b((bq.w - mu) * rr * g1.w + b1.w);
    ushort4* orow = (ushort4*)(xout + row * ND);
    orow[l] = o0;
    orow[64 + l] = o1;
  }
}

// ---------- LayerNorm with bf16 input (residual stream), one wave per row ----------
__global__ __launch_bounds__(256) void ln_bf16_in(const unsigned short* __restrict__ x,
                                                  const float* __restrict__ g,
                                                  const float* __restrict__ bta,
                                                  unsigned short* __restrict__ out) {
  const int t = threadIdx.x, l = t & 63, w = t >> 6;
  const size_t row = (size_t)blockIdx.x * 4 + w;
  const s16x8 v = *(const s16x8*)&x[row * ND + l * 8];
  float xv[8];
  float s = 0.0f, ss = 0.0f;
#pragma unroll
  for (int i = 0; i < 8; ++i) {
    xv[i] = b2f((unsigned short)v[i]);
    s += xv[i];
    ss += xv[i] * xv[i];
  }
#pragma unroll
  for (int msk = 1; msk <= 32; msk <<= 1) {
    s += __shfl_xor(s, msk);
    ss += __shfl_xor(ss, msk);
  }
  float mu = s * (1.0f / ND);
  float var = ss * (1.0f / ND) - mu * mu;
  float rr = rsqrtf(var + 1e-6f);
  const float4* g4 = (const float4*)g;
  const float4* b4 = (const float4*)bta;
  float4 g0 = g4[2 * l], g1 = g4[2 * l + 1];
  float4 b0 = b4[2 * l], b1 = b4[2 * l + 1];
  s16x8 o;
  o[0] = (short)f2b((xv[0] - mu) * rr * g0.x + b0.x);
  o[1] = (short)f2b((xv[1] - mu) * rr * g0.y + b0.y);
  o[2] = (short)f2b((xv[2] - mu) * rr * g0.z + b0.z);
  o[3] = (short)f2b((xv[3] - mu) * rr * g0.w + b0.w);
  o[4] = (short)f2b((xv[4] - mu) * rr * g1.x + b1.x);
  o[5] = (short)f2b((xv[5] - mu) * rr * g1.y + b1.y);
  o[6] = (short)f2b((xv[6] - mu) * rr * g1.z + b1.z);
  o[7] = (short)f2b((xv[7] - mu) * rr * g1.w + b1.w);
  *(s16x8*)&out[row * ND + l * 8] = o;
}

// ---------------- 128x128 MFMA GEMM, 8 waves (wave tile 64x32), BK=64, dbuf ---------
// Used for MLP1 (N=2048, grid 1024, 2 blocks/CU; wide BN keeps A-restage count low).
template <int EPI>
__global__ __launch_bounds__(512) void gemm_bt(const unsigned short* __restrict__ A,
                                               const unsigned short* __restrict__ Bt,
                                               int M, int N, int K,
                                               unsigned short* __restrict__ ob,
                                               float* __restrict__ of,
                                               const float* __restrict__ addf,
                                               const float* __restrict__ bias) {
  __shared__ unsigned short lA[2][128 * 64];
  __shared__ unsigned short lB[2][128 * 64];
  const int t = threadIdx.x;
  const int l = t & 63, w = t >> 6;
  const int wr = w >> 2, wc = w & 3;  // 2x4 wave grid, per-wave 64x32
  const int gx = gridDim.x;
  const int nwg = gx * gridDim.y;
  const int fid = blockIdx.y * gx + blockIdx.x;
  const int q8 = nwg >> 3, r8 = nwg & 7, xcd = fid & 7, idx = fid >> 3;
  const int lid = (xcd < r8 ? xcd * (q8 + 1) : r8 * (q8 + 1) + (xcd - r8) * q8) + idx;
  const int bm = lid / gx, bn = lid % gx;
  const size_t rowBytes = (size_t)K * 2;
  const char* Ab = (const char*)A + (size_t)bm * 128 * rowBytes;
  const char* Bb = (const char*)Bt + (size_t)bn * 128 * rowBytes;
  const int sr0 = t >> 3;
  const int scb = (((t & 7) ^ ((t >> 3) & 7)) << 4);
  f32x4 acc[4][2] = {};

  auto stage = [&](int buf, int k0) {
    char* dA = (char*)&lA[buf][0] + t * 16;
    char* dB = (char*)&lB[buf][0] + t * 16;
#pragma unroll
    for (int i = 0; i < 2; ++i) {
      const size_t go = (size_t)(sr0 + i * 64) * rowBytes + 2 * k0 + scb;
      gload16(Ab + go, dA + i * 8192);
      gload16(Bb + go, dB + i * 8192);
    }
  };

  const int nkt = K >> 6;
  stage(0, 0);
  int cur = 0;
  for (int kt = 0; kt < nkt; ++kt) {
    if (kt + 1 < nkt) {
      stage(cur ^ 1, (kt + 1) * 64);
      asm volatile("s_waitcnt vmcnt(4)" ::: "memory");
    } else {
      asm volatile("s_waitcnt vmcnt(0)" ::: "memory");
    }
    __builtin_amdgcn_s_barrier();
    __builtin_amdgcn_sched_barrier(0);
#pragma unroll
    for (int ks = 0; ks < 2; ++ks) {
      const int xg = ((ks * 4 + (l >> 4)) ^ (l & 7)) * 8;
      bf16x8 aF[4], bF[2];
#pragma unroll
      for (int m = 0; m < 4; ++m)
        aF[m] = *(const bf16x8*)&lA[cur][(wr * 64 + m * 16 + (l & 15)) * 64 + xg];
#pragma unroll
      for (int n = 0; n < 2; ++n)
        bF[n] = *(const bf16x8*)&lB[cur][(wc * 32 + n * 16 + (l & 15)) * 64 + xg];
      __builtin_amdgcn_s_setprio(1);
#pragma unroll
      for (int m = 0; m < 4; ++m)
#pragma unroll
        for (int n = 0; n < 2; ++n)
          acc[m][n] = __builtin_amdgcn_mfma_f32_16x16x32_bf16(aF[m], bF[n], acc[m][n], 0, 0, 0);
      __builtin_amdgcn_s_setprio(0);
    }
    asm volatile("s_waitcnt lgkmcnt(0)" ::: "memory");
    __builtin_amdgcn_s_barrier();
    cur ^= 1;
  }
#pragma unroll
  for (int m = 0; m < 4; ++m)
#pragma unroll
    for (int n = 0; n < 2; ++n) {
      int row0 = bm * 128 + wr * 64 + m * 16 + (l >> 4) * 4;
      int col = bn * 128 + wc * 32 + n * 16 + (l & 15);
      if constexpr (EPI == 2) {
#pragma unroll
        for (int j = 0; j < 4; ++j) {
          size_t i = (size_t)(row0 + j) * NMLP + col;
          ob[i] = f2b(geluf(acc[m][n][j] + bias[col]));
        }
      } else {
#pragma unroll
        for (int j = 0; j < 4; ++j) {
          size_t i = (size_t)(row0 + j) * ND + col;
          of[i] = acc[m][n][j] + addf[i];
        }
      }
    }
}

// ---------------- 128x64 MFMA GEMM, 4 waves (wave tile 64x32), BK=64, dbuf ----------
// 48 KB LDS -> up to 3 resident blocks/CU. EPI: 0 = QKV scatter;
// 1 = +addf -> bf16 residual; 3 = +bias +b2f(addb) -> fp32 out.
template <int EPI>
__global__ __launch_bounds__(256) void gemm_bt64(const unsigned short* __restrict__ A,
                                                 const unsigned short* __restrict__ Bt,
                                                 int M, int N, int K,
                                                 unsigned short* __restrict__ ob,
                                                 float* __restrict__ of,
                                                 const float* __restrict__ addf,
                                                 const float* __restrict__ bias,
                                                 const unsigned short* __restrict__ addb) {
  __shared__ unsigned short lA[2][128 * 64];
  __shared__ unsigned short lB[2][64 * 64];
  const int t = threadIdx.x;
  const int l = t & 63, w = t >> 6;
  const int wr = w >> 1, wc = w & 1;  // 2x2 wave grid, per-wave 64x32
  const int gx = gridDim.x;           // N/64
  const int nwg = gx * gridDim.y;
  const int fid = blockIdx.y * gx + blockIdx.x;
  const int q8 = nwg >> 3, r8 = nwg & 7, xcd = fid & 7, idx = fid >> 3;
  const int lid = (xcd < r8 ? xcd * (q8 + 1) : r8 * (q8 + 1) + (xcd - r8) * q8) + idx;
  const int bm = lid / gx, bn = lid % gx;
  const size_t rowBytes = (size_t)K * 2;
  const char* Ab = (const char*)A + (size_t)bm * 128 * rowBytes;
  const char* Bb = (const char*)Bt + (size_t)bn * 64 * rowBytes;
  const int sr0 = t >> 3;                              // 0..31
  const int scb = (((t & 7) ^ ((t >> 3) & 7)) << 4);   // row&7 invariant under +32k
  f32x4 acc[4][2] = {};

  auto stage = [&](int buf, int k0) {
    char* dA = (char*)&lA[buf][0] + t * 16;
#pragma unroll
    for (int i = 0; i < 4; ++i) {  // A rows sr0 + 32i (128 rows)
      const size_t go = (size_t)(sr0 + i * 32) * rowBytes + 2 * k0 + scb;
      gload16(Ab + go, dA + i * 4096);
    }
    char* dB = (char*)&lB[buf][0] + t * 16;
#pragma unroll
    for (int i = 0; i < 2; ++i) {  // B rows sr0 + 32i (64 rows)
      const size_t go = (size_t)(sr0 + i * 32) * rowBytes + 2 * k0 + scb;
      gload16(Bb + go, dB + i * 4096);
    }
  };

  const int nkt = K >> 6;
  stage(0, 0);
  int cur = 0;
  for (int kt = 0; kt < nkt; ++kt) {
    if (kt + 1 < nkt) {
      stage(cur ^ 1, (kt + 1) * 64);
      asm volatile("s_waitcnt vmcnt(6)" ::: "memory");
    } else {
      asm volatile("s_waitcnt vmcnt(0)" ::: "memory");
    }
    __builtin_amdgcn_s_barrier();
    __builtin_amdgcn_sched_barrier(0);
#pragma unroll
    for (int ks = 0; ks < 2; ++ks) {
      const int xg = ((ks * 4 + (l >> 4)) ^ (l & 7)) * 8;
      bf16x8 aF[4], bF[2];
#pragma unroll
      for (int m = 0; m < 4; ++m)
        aF[m] = *(const bf16x8*)&lA[cur][(wr * 64 + m * 16 + (l & 15)) * 64 + xg];
#pragma unroll
      for (int n = 0; n < 2; ++n)
        bF[n] = *(const bf16x8*)&lB[cur][(wc * 32 + n * 16 + (l & 15)) * 64 + xg];
      __builtin_amdgcn_s_setprio(1);
#pragma unroll
      for (int m = 0; m < 4; ++m)
#pragma unroll
        for (int n = 0; n < 2; ++n)
          acc[m][n] = __builtin_amdgcn_mfma_f32_16x16x32_bf16(aF[m], bF[n], acc[m][n], 0, 0, 0);
      __builtin_amdgcn_s_setprio(0);
    }
    asm volatile("s_waitcnt lgkmcnt(0)" ::: "memory");
    __builtin_amdgcn_s_barrier();
    cur ^= 1;
  }
#pragma unroll
  for (int m = 0; m < 4; ++m)
#pragma unroll
    for (int n = 0; n < 2; ++n) {
      int row0 = bm * 128 + wr * 64 + m * 16 + (l >> 4) * 4;
      int col = bn * 64 + wc * 32 + n * 16 + (l & 15);
      if constexpr (EPI == 0) {
        int part = col >> 9, nn = col & 511;
        int hh = nn >> 6, hd = nn & 63;
        int b = row0 >> 12, sidx0 = row0 & 4095;
        if (part < 2) {
#pragma unroll
          for (int j = 0; j < 4; ++j)
            ob[((((size_t)part * NB + b) * NH + hh) * NS + sidx0 + j) * NHD + hd] =
                f2b(acc[m][n][j]);
        } else {
          ushort4 o;
          o.x = f2b(acc[m][n][0]);
          o.y = f2b(acc[m][n][1]);
          o.z = f2b(acc[m][n][2]);
          o.w = f2b(acc[m][n][3]);
          *(ushort4*)&ob[(size_t)2 * NB * NH * NS * NHD +
                         (((size_t)b * NH + hh) * NHD + hd) * NS + sidx0] = o;
        }
      } else if constexpr (EPI == 1) {
#pragma unroll
        for (int j = 0; j < 4; ++j) {
          size_t i = (size_t)(row0 + j) * ND + col;
          ob[i] = f2b(acc[m][n][j] + addf[i]);
        }
      } else {
#pragma unroll
        for (int j = 0; j < 4; ++j) {
          size_t i = (size_t)(row0 + j) * ND + col;
          of[i] = acc[m][n][j] + bias[col] + b2f(addb[i]);
        }
      }
    }
}

// ---------------- block-sparse flash attention (v23: barrier-free, 1 wave/block) ----
// 4096 blocks x 64 threads; block = (b, h, qb, 16-row tile). hh = bid&7 keeps the
// head<->XCD L2 mapping (K/V per head ~1 MB, L2-resident). No LDS staging: K and V
// MFMA fragments are read directly from global (L2); waves fully independent -> no
// barriers, latency hidden by 16 waves/CU TLP. pl (P re-fragment) is same-wave LDS.
__global__ __launch_bounds__(64) void attn_sparse(const unsigned short* __restrict__ qm,
                                                  const unsigned short* __restrict__ km,
                                                  const unsigned short* __restrict__ vTg,
                                                  unsigned short* __restrict__ ctx) {
  __shared__ unsigned short pl[16 * 64];
  const int l = threadIdx.x;
  const int bid = blockIdx.x;
  const int hh = bid & 7;
  const int u_ = bid >> 3;        // 0..511
  const int wp = u_ & 7;          // 16-row tile index within the q-block
  const int v_ = u_ >> 3;         // 0..63
  const int b = v_ >> 5;
  const int k_ = v_ & 31;
  const int qb = b ? (31 - k_) : k_;  // complement pairing for balance
  const size_t bh = ((size_t)b * NH + hh) * NS;
  const size_t bhd = ((size_t)b * NH + hh) * NHD;
  const int qrow0 = qb * 128 + wp * 16;
  bf16x8 qa[2];
#pragma unroll
  for (int ks = 0; ks < 2; ++ks)
    qa[ks] = *(const bf16x8*)&qm[(bh + qrow0 + (l & 15)) * NHD + ks * 32 + (l >> 4) * 8];
  f32x4 c[4] = {};
  float mrun[4], lrun[4];
#pragma unroll
  for (int j = 0; j < 4; ++j) { mrun[j] = -1e30f; lrun[j] = 0.0f; }

  const int nsum128 = qb >> 2, rem = qb & 3;
  const int nSumCh = nsum128 + (rem ? 1 : 0);
  const int nch = nSumCh + 1;

  auto keyOf = [&](int c2, int kk) -> int {
    return (c2 < nSumCh) ? ((c2 * 4 + (kk >> 5)) * 128 + 96 + (kk & 31)) : (qb * 128 + kk);
  };

  const int e_ = l & 7, q_ = l >> 4;
  const int kx0 = (q_ ^ e_) * 8;   // pl swizzled read offsets (unchanged from r13)
  const int kx1 = ((4 + q_) ^ e_) * 8;
  const int r4_ = (q_ & 1) << 2;

  for (int ch = 0; ch < nch; ++ch) {
    const bool isLocal = (ch == nch - 1);
    const bool isRem = (rem != 0) && !isLocal && (ch == nsum128);
    const int nT = isLocal ? (wp + 1) : (isRem ? 2 * rem : 8);
    const int nTpl = isLocal ? ((wp | 1) + 1) : nT;
    const int nKs = nTpl >> 1;

    f32x4 sf[8];
#pragma unroll
    for (int n = 0; n < 8; ++n) {
      if (n < nT) {
        const int row = n * 16 + (l & 15);
        const unsigned short* kp = &km[(bh + keyOf(ch, row)) * NHD];
        const bf16x8 k0 = *(const bf16x8*)&kp[q_ * 8];
        const bf16x8 k1 = *(const bf16x8*)&kp[32 + q_ * 8];
        f32x4 a = {};
        a = __builtin_amdgcn_mfma_f32_16x16x32_bf16(qa[0], k0, a, 0, 0, 0);
        a = __builtin_amdgcn_mfma_f32_16x16x32_bf16(qa[1], k1, a, 0, 0, 0);
        if (isLocal && n == wp) {
#pragma unroll
          for (int j = 0; j < 4; ++j)
            if ((l & 15) > q_ * 4 + j) a[j] = -1e9f;
        }
        sf[n] = a;
      }
    }
    float cm[4];
#pragma unroll
    for (int j = 0; j < 4; ++j) cm[j] = -1e30f;
#pragma unroll
    for (int n = 0; n < 8; ++n)
      if (n < nT)
#pragma unroll
        for (int j = 0; j < 4; ++j) cm[j] = fmaxf(cm[j], sf[n][j]);
#pragma unroll
    for (int j = 0; j < 4; ++j) {
      cm[j] = fmaxf(cm[j], __shfl_xor(cm[j], 1));
      cm[j] = fmaxf(cm[j], __shfl_xor(cm[j], 2));
      cm[j] = fmaxf(cm[j], __shfl_xor(cm[j], 4));
      cm[j] = fmaxf(cm[j], __shfl_xor(cm[j], 8));
    }
    // defer-max (log2 domain: 8 nats = 11.5416 bits)
    bool need = false;
#pragma unroll
    for (int j = 0; j < 4; ++j) need |= (cm[j] > mrun[j] + 11.5416f);
    if (__any(need)) {
      float al[4];
#pragma unroll
      for (int j = 0; j < 4; ++j) {
        float nm = fmaxf(mrun[j], cm[j]);
        al[j] = exp2_fast(mrun[j] - nm);
        mrun[j] = nm;
      }
#pragma unroll
      for (int n = 0; n < 4; ++n)
#pragma unroll
        for (int j = 0; j < 4; ++j) c[n][j] *= al[j];
#pragma unroll
      for (int j = 0; j < 4; ++j) lrun[j] *= al[j];
    }
    float rs[4] = {0.f, 0.f, 0.f, 0.f};
#pragma unroll
    for (int n = 0; n < 8; ++n)
      if (n < nT)
#pragma unroll
        for (int j = 0; j < 4; ++j) {
          float p = exp2_fast(sf[n][j] - mrun[j]);
          sf[n][j] = p;
          rs[j] += p;
        }
#pragma unroll
    for (int j = 0; j < 4; ++j) {
      rs[j] += __shfl_xor(rs[j], 1);
      rs[j] += __shfl_xor(rs[j], 2);
      rs[j] += __shfl_xor(rs[j], 4);
      rs[j] += __shfl_xor(rs[j], 8);
      lrun[j] += rs[j];
    }
    // P -> same-wave swizzled LDS; PV with V fragments direct from global V^T
#pragma unroll
    for (int h = 0; h < 2; ++h) {
      if (h * 4 < nTpl) {
#pragma unroll
        for (int n2 = 0; n2 < 4; ++n2) {
          const int n = h * 4 + n2;
          const int cu = n2 * 2 + ((l >> 3) & 1);
#pragma unroll
          for (int j = 0; j < 4; ++j) {
            if (n < nTpl) {
              unsigned short pv = 0;
              if (n < nT) pv = f2b(sf[n][j]);
              const int rowp = q_ * 4 + j;
              pl[rowp * 64 + (cu ^ (r4_ | j)) * 8 + e_] = pv;
            }
          }
        }
#pragma unroll
        for (int ks2 = 0; ks2 < 2; ++ks2) {
          const int ks = h * 2 + ks2;
          if (ks < nKs) {
            const bf16x8 pa =
                *(const bf16x8*)&pl[(l & 15) * 64 + (ks2 ? kx1 : kx0)];
            const int gkv = keyOf(ch, ks * 32 + q_ * 8);
#pragma unroll
            for (int nd = 0; nd < 4; ++nd) {
              const bf16x8 vb =
                  *(const bf16x8*)&vTg[(bhd + nd * 16 + (l & 15)) * NS + gkv];
              c[nd] = __builtin_amdgcn_mfma_f32_16x16x32_bf16(pa, vb, c[nd], 0, 0, 0);
            }
          }
        }
      }
    }
  }
  float rinv[4];
#pragma unroll
  for (int j = 0; j < 4; ++j) rinv[j] = 1.0f / lrun[j];
#pragma unroll
  for (int n = 0; n < 4; ++n)
#pragma unroll
    for (int j = 0; j < 4; ++j) {
      int srow = qrow0 + q_ * 4 + j;
      int col = n * 16 + (l & 15);
      ctx[((size_t)b * NS + srow) * ND + hh * NHD + col] = f2b(c[n][j] * rinv[j]);
    }
}

extern "C" void kernel_launch(void* const* d_in, const int* in_sizes, int n_in,
                              void* d_out, int out_size, void* d_ws, size_t ws_size,
                              hipStream_t stream) {
  (void)in_sizes; (void)n_in; (void)out_size; (void)ws_size;
  const float* inputs = (const float*)d_in[0];
  const float* ln1s = (const float*)d_in[1];
  const float* ln1b = (const float*)d_in[2];
  const float* wq = (const float*)d_in[3];
  const float* wk = (const float*)d_in[4];
  const float* wv = (const float*)d_in[5];
  const float* wo = (const float*)d_in[6];
  const float* ln2s = (const float*)d_in[7];
  const float* ln2b = (const float*)d_in[8];
  const float* w1 = (const float*)d_in[9];
  const float* b1 = (const float*)d_in[10];
  const float* w2 = (const float*)d_in[11];
  const float* b2 = (const float*)d_in[12];
  float* out = (float*)d_out;

  // workspace layout (~95 MB)
  unsigned short* xln = (unsigned short*)d_ws;                 // 8192*512 bf16
  unsigned short* xln2 = xln + (size_t)8192 * 512;             // 8192*512
  unsigned short* ctx = xln2 + (size_t)8192 * 512;             // 8192*512
  unsigned short* qkv = ctx + (size_t)8192 * 512;              // 3 * 8192*512 (Q, K, V^T)
  unsigned short* xresb = qkv + (size_t)3 * 8192 * 512;        // 8192*512 bf16 residual
  unsigned short* hbuf = xresb + (size_t)8192 * 512;           // 8192*2048
  unsigned short* qkvT = hbuf + (size_t)8192 * 2048;           // 1536*512
  unsigned short* woT = qkvT + (size_t)1536 * 512;             // 512*512
  unsigned short* w1T = woT + (size_t)512 * 512;               // 2048*512
  unsigned short* w2T = w1T + (size_t)2048 * 512;              // 512*2048

  prep_ln<<<2816, 256, 0, stream>>>(wq, wk, wv, wo, w1, w2, qkvT, woT, w1T, w2T,
                                    inputs, ln1s, ln1b, xln);
  gemm_bt64<0><<<dim3(24, 64), 256, 0, stream>>>(xln, qkvT, 8192, 1536, 512,
                                                 qkv, nullptr, nullptr, nullptr, nullptr);
  attn_sparse<<<4096, 64, 0, stream>>>(qkv, qkv + (size_t)8192 * 512,
                                       qkv + (size_t)2 * 8192 * 512, ctx);
  gemm_bt64<1><<<dim3(8, 64), 256, 0, stream>>>(ctx, woT, 8192, 512, 512,
                                                xresb, nullptr, inputs, nullptr, nullptr);
  ln_bf16_in<<<2048, 256, 0, stream>>>(xresb, ln2s, ln2b, xln2);
  gemm_bt<2><<<dim3(16, 64), 512, 0, stream>>>(xln2, w1T, 8192, 2048, 512,
                                               hbuf, nullptr, nullptr, b1);
  gemm_bt64<3><<<dim3(8, 64), 256, 0, stream>>>(hbuf, w2T, 8192, 512, 2048,
                                                nullptr, out, nullptr, b2, xresb);
}

// Round 24
// 144.828 us; speedup vs baseline: 1.2715x; 1.2715x over previous
//
#include <hip/hip_runtime.h>
#include <hip/hip_bf16.h>

typedef __attribute__((ext_vector_type(8))) __bf16 bf16x8;
typedef __attribute__((ext_vector_type(8))) short s16x8;
typedef __attribute__((ext_vector_type(4))) float f32x4;

#define NB 2
#define NS 4096
#define ND 512
#define NH 8
#define NHD 64
#define NMLP 2048

__device__ __forceinline__ unsigned short f2b(float f) {
  __hip_bfloat16 h = __float2bfloat16(f);
  return __builtin_bit_cast(unsigned short, h);
}

__device__ __forceinline__ float b2f(unsigned short u) {
  unsigned int x = (unsigned int)u << 16;
  return __builtin_bit_cast(float, x);
}

// gelu(x) = x * sigmoid(2u), u = 0.79788456(x + 0.044715 x^3)
__device__ __forceinline__ float geluf(float x) {
  float u = 0.7978845608028654f * (x + 0.044715f * x * x * x);
  return x / (1.0f + __expf(-2.0f * u));
}

// raw v_exp_f32: 2^x (attention scores kept in log2 domain)
__device__ __forceinline__ float exp2_fast(float x) {
  float r;
  asm("v_exp_f32 %0, %1" : "=v"(r) : "v"(x));
  return r;
}

__device__ __forceinline__ void gload16(const void* g, void* l) {
  __builtin_amdgcn_global_load_lds((const __attribute__((address_space(1))) void*)g,
                                   (__attribute__((address_space(3))) void*)l, 16, 0, 0);
}

// ---- fused: weight transposes (blocks 0..767) + LayerNorm1 (blocks 768..2815) ----
// wq gets 0.125*log2(e) baked in (attention softmax runs in log2 domain).
__global__ __launch_bounds__(256) void prep_ln(const float* __restrict__ wq,
                                               const float* __restrict__ wk,
                                               const float* __restrict__ wv,
                                               const float* __restrict__ wo,
                                               const float* __restrict__ w1,
                                               const float* __restrict__ w2,
                                               unsigned short* __restrict__ qkvT,
                                               unsigned short* __restrict__ woT,
                                               unsigned short* __restrict__ w1T,
                                               unsigned short* __restrict__ w2T,
                                               const float* __restrict__ x,
                                               const float* __restrict__ g,
                                               const float* __restrict__ bta,
                                               unsigned short* __restrict__ xout) {
  __shared__ unsigned short lt[64][66];
  const int t = threadIdx.x;
  if (blockIdx.x < 768) {
    const int tile = blockIdx.x;
    const float* src;
    unsigned short* dst;
    int R, C, tr, tc;
    float sc = 1.0f;
    if (tile < 256) {
      int seg = tile >> 6, tt = tile & 63;
      R = 512; C = 512;
      src = seg == 0 ? wq : seg == 1 ? wk : seg == 2 ? wv : wo;
      dst = (seg < 3) ? (qkvT + ((size_t)seg << 18)) : woT;
      if (seg == 0) sc = 0.18033688011112042f;  // 0.125 * log2(e)
      tr = tt >> 3; tc = tt & 7;
    } else if (tile < 512) {
      int tt = tile - 256;
      R = 512; C = 2048; src = w1; dst = w1T;
      tr = tt >> 5; tc = tt & 31;
    } else {
      int tt = tile - 512;
      R = 2048; C = 512; src = w2; dst = w2T;
      tr = tt >> 3; tc = tt & 7;
    }
    const int r0 = tr * 64, c0 = tc * 64;
    const int fx = t & 15, fy = t >> 4;
#pragma unroll
    for (int p = 0; p < 4; ++p) {
      int rr = p * 16 + fy;
      float4 v = *(const float4*)&src[(size_t)(r0 + rr) * C + c0 + fx * 4];
      lt[rr][fx * 4 + 0] = f2b(v.x * sc);
      lt[rr][fx * 4 + 1] = f2b(v.y * sc);
      lt[rr][fx * 4 + 2] = f2b(v.z * sc);
      lt[rr][fx * 4 + 3] = f2b(v.w * sc);
    }
    __syncthreads();
#pragma unroll
    for (int p = 0; p < 4; ++p) {
      int cc = p * 16 + fy;
      ushort4 o;
      o.x = lt[fx * 4 + 0][cc];
      o.y = lt[fx * 4 + 1][cc];
      o.z = lt[fx * 4 + 2][cc];
      o.w = lt[fx * 4 + 3][cc];
      *(ushort4*)&dst[(size_t)(c0 + cc) * R + r0 + fx * 4] = o;
    }
  } else {
    const int l = t & 63, w = t >> 6;
    const size_t row = (size_t)(blockIdx.x - 768) * 4 + w;
    const float4* xr = (const float4*)(x + row * ND);
    float4 a = xr[l];
    float4 bq = xr[64 + l];
    float s = a.x + a.y + a.z + a.w + bq.x + bq.y + bq.z + bq.w;
    float ss = a.x * a.x + a.y * a.y + a.z * a.z + a.w * a.w +
               bq.x * bq.x + bq.y * bq.y + bq.z * bq.z + bq.w * bq.w;
#pragma unroll
    for (int msk = 1; msk <= 32; msk <<= 1) {
      s += __shfl_xor(s, msk);
      ss += __shfl_xor(ss, msk);
    }
    float mu = s * (1.0f / ND);
    float var = ss * (1.0f / ND) - mu * mu;
    float rr = rsqrtf(var + 1e-6f);
    const float4* g4 = (const float4*)g;
    const float4* b4 = (const float4*)bta;
    float4 g0 = g4[l], g1 = g4[64 + l], b0 = b4[l], b1 = b4[64 + l];
    ushort4 o0, o1;
    o0.x = f2b((a.x - mu) * rr * g0.x + b0.x);
    o0.y = f2b((a.y - mu) * rr * g0.y + b0.y);
    o0.z = f2b((a.z - mu) * rr * g0.z + b0.z);
    o0.w = f2b((a.w - mu) * rr * g0.w + b0.w);
    o1.x = f2b((bq.x - mu) * rr * g1.x + b1.x);
    o1.y = f2b((bq.y - mu) * rr * g1.y + b1.y);
    o1.z = f2b((bq.z - mu) * rr * g1.z + b1.z);
    o1.w = f2b((bq.w - mu) * rr * g1.w + b1.w);
    ushort4* orow = (ushort4*)(xout + row * ND);
    orow[l] = o0;
    orow[64 + l] = o1;
  }
}

// ---------- LayerNorm with bf16 input (residual stream), one wave per row ----------
__global__ __launch_bounds__(256) void ln_bf16_in(const unsigned short* __restrict__ x,
                                                  const float* __restrict__ g,
                                                  const float* __restrict__ bta,
                                                  unsigned short* __restrict__ out) {
  const int t = threadIdx.x, l = t & 63, w = t >> 6;
  const size_t row = (size_t)blockIdx.x * 4 + w;
  const s16x8 v = *(const s16x8*)&x[row * ND + l * 8];
  float xv[8];
  float s = 0.0f, ss = 0.0f;
#pragma unroll
  for (int i = 0; i < 8; ++i) {
    xv[i] = b2f((unsigned short)v[i]);
    s += xv[i];
    ss += xv[i] * xv[i];
  }
#pragma unroll
  for (int msk = 1; msk <= 32; msk <<= 1) {
    s += __shfl_xor(s, msk);
    ss += __shfl_xor(ss, msk);
  }
  float mu = s * (1.0f / ND);
  float var = ss * (1.0f / ND) - mu * mu;
  float rr = rsqrtf(var + 1e-6f);
  const float4* g4 = (const float4*)g;
  const float4* b4 = (const float4*)bta;
  float4 g0 = g4[2 * l], g1 = g4[2 * l + 1];
  float4 b0 = b4[2 * l], b1 = b4[2 * l + 1];
  s16x8 o;
  o[0] = (short)f2b((xv[0] - mu) * rr * g0.x + b0.x);
  o[1] = (short)f2b((xv[1] - mu) * rr * g0.y + b0.y);
  o[2] = (short)f2b((xv[2] - mu) * rr * g0.z + b0.z);
  o[3] = (short)f2b((xv[3] - mu) * rr * g0.w + b0.w);
  o[4] = (short)f2b((xv[4] - mu) * rr * g1.x + b1.x);
  o[5] = (short)f2b((xv[5] - mu) * rr * g1.y + b1.y);
  o[6] = (short)f2b((xv[6] - mu) * rr * g1.z + b1.z);
  o[7] = (short)f2b((xv[7] - mu) * rr * g1.w + b1.w);
  *(s16x8*)&out[row * ND + l * 8] = o;
}

// ---------------- 128x128 MFMA GEMM, 8 waves (wave tile 64x32), BK=64, dbuf ---------
// Used for MLP1 (N=2048, grid 1024, 2 blocks/CU; wide BN keeps A-restage count low).
template <int EPI>
__global__ __launch_bounds__(512) void gemm_bt(const unsigned short* __restrict__ A,
                                               const unsigned short* __restrict__ Bt,
                                               int M, int N, int K,
                                               unsigned short* __restrict__ ob,
                                               float* __restrict__ of,
                                               const float* __restrict__ addf,
                                               const float* __restrict__ bias) {
  __shared__ unsigned short lA[2][128 * 64];
  __shared__ unsigned short lB[2][128 * 64];
  const int t = threadIdx.x;
  const int l = t & 63, w = t >> 6;
  const int wr = w >> 2, wc = w & 3;  // 2x4 wave grid, per-wave 64x32
  const int gx = gridDim.x;
  const int nwg = gx * gridDim.y;
  const int fid = blockIdx.y * gx + blockIdx.x;
  const int q8 = nwg >> 3, r8 = nwg & 7, xcd = fid & 7, idx = fid >> 3;
  const int lid = (xcd < r8 ? xcd * (q8 + 1) : r8 * (q8 + 1) + (xcd - r8) * q8) + idx;
  const int bm = lid / gx, bn = lid % gx;
  const size_t rowBytes = (size_t)K * 2;
  const char* Ab = (const char*)A + (size_t)bm * 128 * rowBytes;
  const char* Bb = (const char*)Bt + (size_t)bn * 128 * rowBytes;
  const int sr0 = t >> 3;
  const int scb = (((t & 7) ^ ((t >> 3) & 7)) << 4);
  f32x4 acc[4][2] = {};

  auto stage = [&](int buf, int k0) {
    char* dA = (char*)&lA[buf][0] + t * 16;
    char* dB = (char*)&lB[buf][0] + t * 16;
#pragma unroll
    for (int i = 0; i < 2; ++i) {
      const size_t go = (size_t)(sr0 + i * 64) * rowBytes + 2 * k0 + scb;
      gload16(Ab + go, dA + i * 8192);
      gload16(Bb + go, dB + i * 8192);
    }
  };

  const int nkt = K >> 6;
  stage(0, 0);
  int cur = 0;
  for (int kt = 0; kt < nkt; ++kt) {
    if (kt + 1 < nkt) {
      stage(cur ^ 1, (kt + 1) * 64);
      asm volatile("s_waitcnt vmcnt(4)" ::: "memory");
    } else {
      asm volatile("s_waitcnt vmcnt(0)" ::: "memory");
    }
    __builtin_amdgcn_s_barrier();
    __builtin_amdgcn_sched_barrier(0);
#pragma unroll
    for (int ks = 0; ks < 2; ++ks) {
      const int xg = ((ks * 4 + (l >> 4)) ^ (l & 7)) * 8;
      bf16x8 aF[4], bF[2];
#pragma unroll
      for (int m = 0; m < 4; ++m)
        aF[m] = *(const bf16x8*)&lA[cur][(wr * 64 + m * 16 + (l & 15)) * 64 + xg];
#pragma unroll
      for (int n = 0; n < 2; ++n)
        bF[n] = *(const bf16x8*)&lB[cur][(wc * 32 + n * 16 + (l & 15)) * 64 + xg];
      __builtin_amdgcn_s_setprio(1);
#pragma unroll
      for (int m = 0; m < 4; ++m)
#pragma unroll
        for (int n = 0; n < 2; ++n)
          acc[m][n] = __builtin_amdgcn_mfma_f32_16x16x32_bf16(aF[m], bF[n], acc[m][n], 0, 0, 0);
      __builtin_amdgcn_s_setprio(0);
    }
    asm volatile("s_waitcnt lgkmcnt(0)" ::: "memory");
    __builtin_amdgcn_s_barrier();
    cur ^= 1;
  }
#pragma unroll
  for (int m = 0; m < 4; ++m)
#pragma unroll
    for (int n = 0; n < 2; ++n) {
      int row0 = bm * 128 + wr * 64 + m * 16 + (l >> 4) * 4;
      int col = bn * 128 + wc * 32 + n * 16 + (l & 15);
      if constexpr (EPI == 2) {
#pragma unroll
        for (int j = 0; j < 4; ++j) {
          size_t i = (size_t)(row0 + j) * NMLP + col;
          ob[i] = f2b(geluf(acc[m][n][j] + bias[col]));
        }
      } else {
#pragma unroll
        for (int j = 0; j < 4; ++j) {
          size_t i = (size_t)(row0 + j) * ND + col;
          of[i] = acc[m][n][j] + addf[i];
        }
      }
    }
}

// ---------------- 128x64 MFMA GEMM, 4 waves (wave tile 64x32), BK=64, dbuf ----------
// 48 KB LDS -> up to 3 resident blocks/CU. EPI: 0 = QKV scatter;
// 1 = +addf -> bf16 residual; 3 = +bias +b2f(addb) -> fp32 out.
template <int EPI>
__global__ __launch_bounds__(256) void gemm_bt64(const unsigned short* __restrict__ A,
                                                 const unsigned short* __restrict__ Bt,
                                                 int M, int N, int K,
                                                 unsigned short* __restrict__ ob,
                                                 float* __restrict__ of,
                                                 const float* __restrict__ addf,
                                                 const float* __restrict__ bias,
                                                 const unsigned short* __restrict__ addb) {
  __shared__ unsigned short lA[2][128 * 64];
  __shared__ unsigned short lB[2][64 * 64];
  const int t = threadIdx.x;
  const int l = t & 63, w = t >> 6;
  const int wr = w >> 1, wc = w & 1;  // 2x2 wave grid, per-wave 64x32
  const int gx = gridDim.x;           // N/64
  const int nwg = gx * gridDim.y;
  const int fid = blockIdx.y * gx + blockIdx.x;
  const int q8 = nwg >> 3, r8 = nwg & 7, xcd = fid & 7, idx = fid >> 3;
  const int lid = (xcd < r8 ? xcd * (q8 + 1) : r8 * (q8 + 1) + (xcd - r8) * q8) + idx;
  const int bm = lid / gx, bn = lid % gx;
  const size_t rowBytes = (size_t)K * 2;
  const char* Ab = (const char*)A + (size_t)bm * 128 * rowBytes;
  const char* Bb = (const char*)Bt + (size_t)bn * 64 * rowBytes;
  const int sr0 = t >> 3;                              // 0..31
  const int scb = (((t & 7) ^ ((t >> 3) & 7)) << 4);   // row&7 invariant under +32k
  f32x4 acc[4][2] = {};

  auto stage = [&](int buf, int k0) {
    char* dA = (char*)&lA[buf][0] + t * 16;
#pragma unroll
    for (int i = 0; i < 4; ++i) {  // A rows sr0 + 32i (128 rows)
      const size_t go = (size_t)(sr0 + i * 32) * rowBytes + 2 * k0 + scb;
      gload16(Ab + go, dA + i * 4096);
    }
    char* dB = (char*)&lB[buf][0] + t * 16;
#pragma unroll
    for (int i = 0; i < 2; ++i) {  // B rows sr0 + 32i (64 rows)
      const size_t go = (size_t)(sr0 + i * 32) * rowBytes + 2 * k0 + scb;
      gload16(Bb + go, dB + i * 4096);
    }
  };

  const int nkt = K >> 6;
  stage(0, 0);
  int cur = 0;
  for (int kt = 0; kt < nkt; ++kt) {
    if (kt + 1 < nkt) {
      stage(cur ^ 1, (kt + 1) * 64);
      asm volatile("s_waitcnt vmcnt(6)" ::: "memory");
    } else {
      asm volatile("s_waitcnt vmcnt(0)" ::: "memory");
    }
    __builtin_amdgcn_s_barrier();
    __builtin_amdgcn_sched_barrier(0);
#pragma unroll
    for (int ks = 0; ks < 2; ++ks) {
      const int xg = ((ks * 4 + (l >> 4)) ^ (l & 7)) * 8;
      bf16x8 aF[4], bF[2];
#pragma unroll
      for (int m = 0; m < 4; ++m)
        aF[m] = *(const bf16x8*)&lA[cur][(wr * 64 + m * 16 + (l & 15)) * 64 + xg];
#pragma unroll
      for (int n = 0; n < 2; ++n)
        bF[n] = *(const bf16x8*)&lB[cur][(wc * 32 + n * 16 + (l & 15)) * 64 + xg];
      __builtin_amdgcn_s_setprio(1);
#pragma unroll
      for (int m = 0; m < 4; ++m)
#pragma unroll
        for (int n = 0; n < 2; ++n)
          acc[m][n] = __builtin_amdgcn_mfma_f32_16x16x32_bf16(aF[m], bF[n], acc[m][n], 0, 0, 0);
      __builtin_amdgcn_s_setprio(0);
    }
    asm volatile("s_waitcnt lgkmcnt(0)" ::: "memory");
    __builtin_amdgcn_s_barrier();
    cur ^= 1;
  }
#pragma unroll
  for (int m = 0; m < 4; ++m)
#pragma unroll
    for (int n = 0; n < 2; ++n) {
      int row0 = bm * 128 + wr * 64 + m * 16 + (l >> 4) * 4;
      int col = bn * 64 + wc * 32 + n * 16 + (l & 15);
      if constexpr (EPI == 0) {
        int part = col >> 9, nn = col & 511;
        int hh = nn >> 6, hd = nn & 63;
        int b = row0 >> 12, sidx0 = row0 & 4095;
        if (part < 2) {
#pragma unroll
          for (int j = 0; j < 4; ++j)
            ob[((((size_t)part * NB + b) * NH + hh) * NS + sidx0 + j) * NHD + hd] =
                f2b(acc[m][n][j]);
        } else {
          ushort4 o;
          o.x = f2b(acc[m][n][0]);
          o.y = f2b(acc[m][n][1]);
          o.z = f2b(acc[m][n][2]);
          o.w = f2b(acc[m][n][3]);
          *(ushort4*)&ob[(size_t)2 * NB * NH * NS * NHD +
                         (((size_t)b * NH + hh) * NHD + hd) * NS + sidx0] = o;
        }
      } else if constexpr (EPI == 1) {
#pragma unroll
        for (int j = 0; j < 4; ++j) {
          size_t i = (size_t)(row0 + j) * ND + col;
          ob[i] = f2b(acc[m][n][j] + addf[i]);
        }
      } else {
#pragma unroll
        for (int j = 0; j < 4; ++j) {
          size_t i = (size_t)(row0 + j) * ND + col;
          of[i] = acc[m][n][j] + bias[col] + b2f(addb[i]);
        }
      }
    }
}

// ---------------- block-sparse flash attention (r13 structure, log2-domain softmax) --
__global__ __launch_bounds__(512, 4) void attn_sparse(const unsigned short* __restrict__ qm,
                                                      const unsigned short* __restrict__ km,
                                                      const unsigned short* __restrict__ vTg,
                                                      unsigned short* __restrict__ ctx) {
  __shared__ unsigned short kl[2][128 * 64];
  __shared__ unsigned short vt[2][64 * 128];
  __shared__ unsigned short pl[8][16 * 64];
  const int t = threadIdx.x, l = t & 63, w = t >> 6;
  const int bid = blockIdx.x;
  const int hh = bid & 7;
  const int jj = bid >> 3;
  const int b = jj >> 5;
  const int qb = (jj < 32) ? jj : 63 - jj;
  const size_t bh = ((size_t)b * NH + hh) * NS;
  const size_t bhd = ((size_t)b * NH + hh) * NHD;
  const int qrow0 = qb * 128 + w * 16;
  bf16x8 qa[2];
#pragma unroll
  for (int ks = 0; ks < 2; ++ks)
    qa[ks] = *(const bf16x8*)&qm[(bh + qrow0 + (l & 15)) * NHD + ks * 32 + (l >> 4) * 8];
  f32x4 c[4] = {};
  float mrun[4], lrun[4];
#pragma unroll
  for (int j = 0; j < 4; ++j) { mrun[j] = -1e30f; lrun[j] = 0.0f; }

  const int nsum128 = qb >> 2, rem = qb & 3;
  const int nSumCh = nsum128 + (rem ? 1 : 0);
  const int nch = nSumCh + 1;

  const int kr_ = t >> 3;
  const int ku_ = (t & 7) ^ (kr_ & 7);
  const int vr_ = t >> 4;
  const int vu_ = ((t & 15) & 8) | (((t & 15) & 7) ^ (vr_ & 7));

  auto keyOf = [&](int c2, int kk) -> int {
    return (c2 < nSumCh) ? ((c2 * 4 + (kk >> 5)) * 128 + 96 + (kk & 31)) : (qb * 128 + kk);
  };
  auto stage = [&](int buf, int c2) {
    const int krow0 = keyOf(c2, kr_);
    gload16(&km[(bh + krow0) * NHD + ku_ * 8], (char*)&kl[buf][0] + t * 16);
    const int krow1 = keyOf(c2, kr_ + 64);
    gload16(&km[(bh + krow1) * NHD + ku_ * 8], (char*)&kl[buf][0] + 8192 + t * 16);
    const int gk = keyOf(c2, vu_ * 8);
    gload16(&vTg[(bhd + vr_) * NS + gk], (char*)&vt[buf][0] + t * 16);
    gload16(&vTg[(bhd + vr_ + 32) * NS + gk], (char*)&vt[buf][0] + 8192 + t * 16);
  };

  const int e_ = l & 7, q_ = l >> 4;
  const int kx0 = (q_ ^ e_) * 8;
  const int kx1 = ((4 + q_) ^ e_) * 8;
  const int r4_ = (q_ & 1) << 2;

  stage(0, 0);
  int cur = 0;
  for (int ch = 0; ch < nch; ++ch) {
    if (ch + 1 < nch) {
      stage(cur ^ 1, ch + 1);
      asm volatile("s_waitcnt vmcnt(4)" ::: "memory");
    } else {
      asm volatile("s_waitcnt vmcnt(0)" ::: "memory");
    }
    __builtin_amdgcn_s_barrier();
    __builtin_amdgcn_sched_barrier(0);

    const bool isLocal = (ch == nch - 1);
    const bool isRem = (rem != 0) && !isLocal && (ch == nsum128);
    const int nT = isLocal ? (w + 1) : (isRem ? 2 * rem : 8);
    const int nTpl = isLocal ? ((w | 1) + 1) : nT;
    const int nKs = nTpl >> 1;

    f32x4 sf[8];
#pragma unroll
    for (int n = 0; n < 8; ++n) {
      if (n < nT) {
        const int row = n * 16 + (l & 15);
        const bf16x8 k0 = *(const bf16x8*)&kl[cur][row * 64 + kx0];
        const bf16x8 k1 = *(const bf16x8*)&kl[cur][row * 64 + kx1];
        f32x4 a = {};
        a = __builtin_amdgcn_mfma_f32_16x16x32_bf16(qa[0], k0, a, 0, 0, 0);
        a = __builtin_amdgcn_mfma_f32_16x16x32_bf16(qa[1], k1, a, 0, 0, 0);
        if (isLocal && n == w) {
#pragma unroll
          for (int j = 0; j < 4; ++j)
            if ((l & 15) > q_ * 4 + j) a[j] = -1e9f;
        }
        sf[n] = a;
      }
    }
    float cm[4];
#pragma unroll
    for (int j = 0; j < 4; ++j) cm[j] = -1e30f;
#pragma unroll
    for (int n = 0; n < 8; ++n)
      if (n < nT)
#pragma unroll
        for (int j = 0; j < 4; ++j) cm[j] = fmaxf(cm[j], sf[n][j]);
#pragma unroll
    for (int j = 0; j < 4; ++j) {
      cm[j] = fmaxf(cm[j], __shfl_xor(cm[j], 1));
      cm[j] = fmaxf(cm[j], __shfl_xor(cm[j], 2));
      cm[j] = fmaxf(cm[j], __shfl_xor(cm[j], 4));
      cm[j] = fmaxf(cm[j], __shfl_xor(cm[j], 8));
    }
    // defer-max (log2 domain: 8 nats = 11.5416 bits)
    bool need = false;
#pragma unroll
    for (int j = 0; j < 4; ++j) need |= (cm[j] > mrun[j] + 11.5416f);
    if (__any(need)) {
      float al[4];
#pragma unroll
      for (int j = 0; j < 4; ++j) {
        float nm = fmaxf(mrun[j], cm[j]);
        al[j] = exp2_fast(mrun[j] - nm);
        mrun[j] = nm;
      }
#pragma unroll
      for (int n = 0; n < 4; ++n)
#pragma unroll
        for (int j = 0; j < 4; ++j) c[n][j] *= al[j];
#pragma unroll
      for (int j = 0; j < 4; ++j) lrun[j] *= al[j];
    }
    float rs[4] = {0.f, 0.f, 0.f, 0.f};
#pragma unroll
    for (int n = 0; n < 8; ++n)
      if (n < nT)
#pragma unroll
        for (int j = 0; j < 4; ++j) {
          float p = exp2_fast(sf[n][j] - mrun[j]);
          sf[n][j] = p;
          rs[j] += p;
        }
#pragma unroll
    for (int j = 0; j < 4; ++j) {
      rs[j] += __shfl_xor(rs[j], 1);
      rs[j] += __shfl_xor(rs[j], 2);
      rs[j] += __shfl_xor(rs[j], 4);
      rs[j] += __shfl_xor(rs[j], 8);
      lrun[j] += rs[j];
    }
#pragma unroll
    for (int h = 0; h < 2; ++h) {
      if (h * 4 < nTpl) {
#pragma unroll
        for (int n2 = 0; n2 < 4; ++n2) {
          const int n = h * 4 + n2;
          const int cu = n2 * 2 + ((l >> 3) & 1);
#pragma unroll
          for (int j = 0; j < 4; ++j) {
            if (n < nTpl) {
              unsigned short pv = 0;
              if (n < nT) pv = f2b(sf[n][j]);
              const int rowp = q_ * 4 + j;
              pl[w][rowp * 64 + (cu ^ (r4_ | j)) * 8 + e_] = pv;
            }
          }
        }
#pragma unroll
        for (int ks2 = 0; ks2 < 2; ++ks2) {
          const int ks = h * 2 + ks2;
          if (ks < nKs) {
            const bf16x8 pa =
                *(const bf16x8*)&pl[w][(l & 15) * 64 + (ks2 ? kx1 : kx0)];
#pragma unroll
            for (int nd = 0; nd < 4; ++nd) {
              const bf16x8 vb = *(const bf16x8*)&vt[cur][(nd * 16 + (l & 15)) * 128 +
                                                         ((ks & 2) << 5) +
                                                         (ks2 ? kx1 : kx0)];
              c[nd] = __builtin_amdgcn_mfma_f32_16x16x32_bf16(pa, vb, c[nd], 0, 0, 0);
            }
          }
        }
      }
    }
    __builtin_amdgcn_s_barrier();
    cur ^= 1;
  }
  float rinv[4];
#pragma unroll
  for (int j = 0; j < 4; ++j) rinv[j] = 1.0f / lrun[j];
#pragma unroll
  for (int n = 0; n < 4; ++n)
#pragma unroll
    for (int j = 0; j < 4; ++j) {
      int srow = qrow0 + q_ * 4 + j;
      int col = n * 16 + (l & 15);
      ctx[((size_t)b * NS + srow) * ND + hh * NHD + col] = f2b(c[n][j] * rinv[j]);
    }
}

extern "C" void kernel_launch(void* const* d_in, const int* in_sizes, int n_in,
                              void* d_out, int out_size, void* d_ws, size_t ws_size,
                              hipStream_t stream) {
  (void)in_sizes; (void)n_in; (void)out_size; (void)ws_size;
  const float* inputs = (const float*)d_in[0];
  const float* ln1s = (const float*)d_in[1];
  const float* ln1b = (const float*)d_in[2];
  const float* wq = (const float*)d_in[3];
  const float* wk = (const float*)d_in[4];
  const float* wv = (const float*)d_in[5];
  const float* wo = (const float*)d_in[6];
  const float* ln2s = (const float*)d_in[7];
  const float* ln2b = (const float*)d_in[8];
  const float* w1 = (const float*)d_in[9];
  const float* b1 = (const float*)d_in[10];
  const float* w2 = (const float*)d_in[11];
  const float* b2 = (const float*)d_in[12];
  float* out = (float*)d_out;

  // workspace layout (~95 MB)
  unsigned short* xln = (unsigned short*)d_ws;                 // 8192*512 bf16
  unsigned short* xln2 = xln + (size_t)8192 * 512;             // 8192*512
  unsigned short* ctx = xln2 + (size_t)8192 * 512;             // 8192*512
  unsigned short* qkv = ctx + (size_t)8192 * 512;              // 3 * 8192*512 (Q, K, V^T)
  unsigned short* xresb = qkv + (size_t)3 * 8192 * 512;        // 8192*512 bf16 residual
  unsigned short* hbuf = xresb + (size_t)8192 * 512;           // 8192*2048
  unsigned short* qkvT = hbuf + (size_t)8192 * 2048;           // 1536*512
  unsigned short* woT = qkvT + (size_t)1536 * 512;             // 512*512
  unsigned short* w1T = woT + (size_t)512 * 512;               // 2048*512
  unsigned short* w2T = w1T + (size_t)2048 * 512;              // 512*2048

  prep_ln<<<2816, 256, 0, stream>>>(wq, wk, wv, wo, w1, w2, qkvT, woT, w1T, w2T,
                                    inputs, ln1s, ln1b, xln);
  gemm_bt64<0><<<dim3(24, 64), 256, 0, stream>>>(xln, qkvT, 8192, 1536, 512,
                                                 qkv, nullptr, nullptr, nullptr, nullptr);
  attn_sparse<<<512, 512, 0, stream>>>(qkv, qkv + (size_t)8192 * 512,
                                       qkv + (size_t)2 * 8192 * 512, ctx);
  gemm_bt64<1><<<dim3(8, 64), 256, 0, stream>>>(ctx, woT, 8192, 512, 512,
                                                xresb, nullptr, inputs, nullptr, nullptr);
  ln_bf16_in<<<2048, 256, 0, stream>>>(xresb, ln2s, ln2b, xln2);
  gemm_bt<2><<<dim3(16, 64), 512, 0, stream>>>(xln2, w1T, 8192, 2048, 512,
                                               hbuf, nullptr, nullptr, b1);
  gemm_bt64<3><<<dim3(8, 64), 256, 0, stream>>>(hbuf, w2T, 8192, 512, 2048,
                                                nullptr, out, nullptr, b2, xresb);
}